// Round 3
// baseline (580.203 us; speedup 1.0000x reference)
//
#include <hip/hip_runtime.h>

#define VOCAB 21
#define EMB 128
#define H1 64
#define H2 100
#define T1 500
#define TP 100
#define NB 1024
#define TBL_LD 260

typedef __attribute__((ext_vector_type(8))) short bf16x8;
typedef __attribute__((ext_vector_type(4))) float f32x4;

__device__ __forceinline__ float sigf(float x){ return 1.0f/(1.0f+__expf(-x)); }
__device__ __forceinline__ float tanhf_(float x){ return 1.0f - 2.0f/(1.0f+__expf(2.0f*x)); }
__device__ __forceinline__ unsigned short f2bf(float x){
    union { float f; unsigned u; } v; v.f = x;
    return (unsigned short)((v.u + 0x7FFFu + ((v.u >> 16) & 1u)) >> 16);
}

// ---------------------------------------------------------------------------
// Kernel 0: permuted xproj table. table[v][4*cell+gate] =
//   dot(W_ih1[gate*64+cell,:], emb[v,:]) + b_ih1[..] + b_hh1[..]
// ---------------------------------------------------------------------------
__global__ void k_table(const float* __restrict__ Wih, const float* __restrict__ emb,
                        const float* __restrict__ bih, const float* __restrict__ bhh,
                        float* __restrict__ table){
    const int p = threadIdx.x;           // permuted gate-col 0..255
    const int v = blockIdx.x;
    const int orig = (p & 3) * H1 + (p >> 2);
    float s = bih[orig] + bhh[orig];
    if (v != 0){
        const float* w = Wih + orig * EMB;
        const float* e = emb + v * EMB;
        #pragma unroll 16
        for (int d = 0; d < EMB; ++d) s += w[d]*e[d];
    }
    table[v*TBL_LD + p] = s;
}

// ---------------------------------------------------------------------------
// Kernel 1: layer-1 LSTM. 16 rows/block, 64 blocks, 8 waves.
// Wave w owns gate tiles {2w, 2w+1}. Cell update is register-local from the
// MFMA acc (p = 4*cell+gate permutation); ping-pong h buffer, 1 barrier/step.
// ---------------------------------------------------------------------------
__global__ __launch_bounds__(512, 2) void k_lstm1(
    const int* __restrict__ xidx, const float* __restrict__ Whh,
    const float* __restrict__ tbl_g, float* __restrict__ x2){
  __shared__ __align__(16) float table[VOCAB*TBL_LD];        // 21840 B
  __shared__ __align__(16) unsigned short hbuf[2][16*64];    // 4096 B, XOR-swizzled
  __shared__ int idxs[16*T1];                                // 32000 B

  const int tid = threadIdx.x;
  const int w = tid >> 6, l = tid & 63;
  const int b0 = blockIdx.x * 16;
  const int row = l & 15, kg = l >> 4;

  for (int i = tid; i < VOCAB*TBL_LD; i += 512) table[i] = tbl_g[i];
  for (int i = tid; i < 16*T1; i += 512){
      int r = i / T1, t = i - r*T1;
      idxs[i] = xidx[(b0 + r)*T1 + t];
  }
  for (int i = tid; i < 16*64; i += 512) hbuf[0][i] = 0;     // t=0 reads buf 0

  // A fragments: tiles T = 2w+u, A row m = l&15, k = 32c + 8*kg + j
  bf16x8 af[2][2];
  #pragma unroll
  for (int u = 0; u < 2; ++u){
      const int p = 16*(2*w + u) + row;
      const int orig = (p & 3)*H1 + (p >> 2);
      #pragma unroll
      for (int c = 0; c < 2; ++c){
          const float* src = Whh + orig*H1 + c*32 + kg*8;
          bf16x8 f;
          #pragma unroll
          for (int j = 0; j < 8; ++j) f[j] = (short)f2bf(src[j]);
          af[u][c] = f;
      }
  }

  const int cell0 = 8*w + kg;        // tile 2w   : cell = 4*(2w)+kg
  const int cell1 = 8*w + 4 + kg;    // tile 2w+1
  char* hb = (char*)hbuf;
  const int swz = (row & 7) << 4;
  const int rb0 = (row*128 + 16*kg) ^ swz;
  const int rb1 = (row*128 + 64 + 16*kg) ^ swz;
  const int wb0 = (row*128 + 2*cell0) ^ swz;
  const int wb1 = (row*128 + 2*cell1) ^ swz;

  float cc0 = 0.f, cc1 = 0.f, pm0 = -1e30f, pm1 = -1e30f;
  __syncthreads();

  // prefetch xproj quads for t=0
  int v0 = idxs[row*T1];
  f32x4 tv0 = *(const f32x4*)&table[v0*TBL_LD + 4*cell0];
  f32x4 tv1 = *(const f32x4*)&table[v0*TBL_LD + 4*cell1];

  for (int t = 0; t < T1; ++t){
      const int rp = (t & 1) ? 2048 : 0, wp = rp ^ 2048;
      bf16x8 bf0 = *(const bf16x8*)(hb + rp + rb0);
      bf16x8 bf1 = *(const bf16x8*)(hb + rp + rb1);
      f32x4 a0 = __builtin_amdgcn_mfma_f32_16x16x32_bf16(af[0][0], bf0, tv0, 0,0,0);
      a0       = __builtin_amdgcn_mfma_f32_16x16x32_bf16(af[0][1], bf1, a0, 0,0,0);
      f32x4 a1 = __builtin_amdgcn_mfma_f32_16x16x32_bf16(af[1][0], bf0, tv1, 0,0,0);
      a1       = __builtin_amdgcn_mfma_f32_16x16x32_bf16(af[1][1], bf1, a1, 0,0,0);
      if (t + 1 < T1){                       // prefetch next xproj (idx-only dep)
          int vn = idxs[row*T1 + t + 1];
          tv0 = *(const f32x4*)&table[vn*TBL_LD + 4*cell0];
          tv1 = *(const f32x4*)&table[vn*TBL_LD + 4*cell1];
      }
      cc0 = sigf(a0[1])*cc0 + sigf(a0[0])*tanhf_(a0[2]);
      float h0 = sigf(a0[3])*tanhf_(cc0);
      cc1 = sigf(a1[1])*cc1 + sigf(a1[0])*tanhf_(a1[2]);
      float h1 = sigf(a1[3])*tanhf_(cc1);
      *(unsigned short*)(hb + wp + wb0) = f2bf(h0);
      *(unsigned short*)(hb + wp + wb1) = f2bf(h1);
      pm0 = fmaxf(pm0, h0); pm1 = fmaxf(pm1, h1);
      if ((t % 5) == 4){
          float* dst = x2 + (b0 + row)*(TP*H1) + (t/5)*H1;
          dst[cell0] = pm0; dst[cell1] = pm1;
          pm0 = -1e30f; pm1 = -1e30f;
      }
      __syncthreads();                       // single barrier per step
  }
}

// ---------------------------------------------------------------------------
// Kernel 2: layer-2 LSTM. 16 rows/block, 64 blocks, 8 waves; 26 gate tiles
// (cells padded to 104, zero weights) split 4,4,3,3,3,3,3,3 over waves.
// B = [x(64) | h(100, pad to 128)] bf16, ping-pong, 1 barrier/step.
// ---------------------------------------------------------------------------
__global__ __launch_bounds__(512, 2) void k_lstm2(
    const float* __restrict__ x2, const float* __restrict__ Wih,
    const float* __restrict__ Whh, const float* __restrict__ bih,
    const float* __restrict__ bhh, const float* __restrict__ fcw,
    const float* __restrict__ fcb, float* __restrict__ out){
  __shared__ __align__(16) unsigned short blds[2][16*192];   // 12288 B
  __shared__ float fcred[8][16];

  const int tid = threadIdx.x;
  const int w = tid >> 6, l = tid & 63;
  const int b0 = blockIdx.x * 16;
  const int row = l & 15, kg = l >> 4;
  const int tlo = (w < 2) ? 4*w : 8 + 3*(w - 2);
  const int nt  = (w < 2) ? 4 : 3;

  for (int i = tid; i < 16*192; i += 512){ blds[0][i] = 0; blds[1][i] = 0; }

  // A fragments: [W_ih2 | W_hh2] permuted, zero-padded (k>=164 or cell>=100)
  bf16x8 af[4][6];
  #pragma unroll
  for (int u = 0; u < 4; ++u){
      if (u < nt){
          const int p = 16*(tlo + u) + row;
          const int cell = p >> 2, gate = p & 3;
          #pragma unroll
          for (int c = 0; c < 6; ++c){
              bf16x8 f;
              #pragma unroll
              for (int j = 0; j < 8; ++j){
                  int k = c*32 + kg*8 + j;
                  float vv = 0.f;
                  if (cell < H2){
                      if (k < 64)           vv = Wih[(gate*H2 + cell)*H1 + k];
                      else if (k < 64 + H2) vv = Whh[(gate*H2 + cell)*H2 + (k - 64)];
                  }
                  f[j] = (short)f2bf(vv);
              }
              af[u][c] = f;
          }
      }
  }

  int cellu[4];
  f32x4 bz[4];
  float fw[4];
  #pragma unroll
  for (int u = 0; u < 4; ++u){
      const int cu = 4*(tlo + u) + kg;
      cellu[u] = cu;
      f32x4 b = {0.f,0.f,0.f,0.f};
      float fv = 0.f;
      if (u < nt && cu < H2){
          #pragma unroll
          for (int g = 0; g < 4; ++g) b[g] = bih[g*H2 + cu] + bhh[g*H2 + cu];
          fv = fcw[cu];
      }
      bz[u] = b; fw[u] = fv;
  }

  char* bb = (char*)blds;
  const int swz = (row & 7) << 4;
  int rb[6];
  #pragma unroll
  for (int c = 0; c < 6; ++c) rb[c] = (row*384 + 64*c + 16*kg) ^ swz;
  int wbh[4];
  #pragma unroll
  for (int u = 0; u < 4; ++u) wbh[u] = (row*384 + 2*(64 + cellu[u])) ^ swz;

  // x staging role: thread stages 2 cells of one row per step
  const int xr = tid >> 5, xc = tid & 31;
  const int xwb = (xr*384 + 4*xc) ^ ((xr & 7) << 4);
  {
      const float2 v = *(const float2*)&x2[(b0 + xr)*(TP*H1) + 2*xc];
      unsigned pk = (unsigned)f2bf(v.x) | ((unsigned)f2bf(v.y) << 16);
      *(unsigned*)(bb + xwb) = pk;           // buf 0, t=0
  }
  float cc[4] = {0.f,0.f,0.f,0.f};
  float hh[4] = {0.f,0.f,0.f,0.f};
  __syncthreads();

  for (int t = 0; t < TP; ++t){
      const int rp = (t & 1) ? 6144 : 0, wp = rp ^ 6144;
      float2 xn = {0.f, 0.f};
      if (t + 1 < TP)                        // T14 issue-early
          xn = *(const float2*)&x2[(b0 + xr)*(TP*H1) + (t+1)*64 + 2*xc];
      bf16x8 bf[6];
      #pragma unroll
      for (int c = 0; c < 6; ++c) bf[c] = *(const bf16x8*)(bb + rp + rb[c]);
      f32x4 ac[4];
      #pragma unroll
      for (int u = 0; u < 4; ++u){
          if (u < nt){
              f32x4 z = bz[u];
              #pragma unroll
              for (int c = 0; c < 6; ++c)
                  z = __builtin_amdgcn_mfma_f32_16x16x32_bf16(af[u][c], bf[c], z, 0,0,0);
              ac[u] = z;
          }
      }
      #pragma unroll
      for (int u = 0; u < 4; ++u){
          if (u < nt){
              f32x4 a = ac[u];
              cc[u] = sigf(a[1])*cc[u] + sigf(a[0])*tanhf_(a[2]);
              float h = sigf(a[3])*tanhf_(cc[u]);
              hh[u] = h;
              *(unsigned short*)(bb + wp + wbh[u]) = f2bf(h);
          }
      }
      if (t + 1 < TP){                       // write-late
          unsigned pk = (unsigned)f2bf(xn.x) | ((unsigned)f2bf(xn.y) << 16);
          *(unsigned*)(bb + wp + xwb) = pk;
      }
      __syncthreads();
  }

  // FC + sigmoid: reduce over this lane's cells, then kg (lanes 16,32), then waves
  float p = 0.f;
  #pragma unroll
  for (int u = 0; u < 4; ++u) if (u < nt) p += hh[u] * fw[u];
  p += __shfl_xor(p, 16);
  p += __shfl_xor(p, 32);
  if (l < 16) fcred[w][l] = p;
  __syncthreads();
  if (tid < 16){
      float s = 0.f;
      #pragma unroll
      for (int ww = 0; ww < 8; ++ww) s += fcred[ww][tid];
      out[b0 + tid] = sigf(s + fcb[0]);
  }
}

// ---------------------------------------------------------------------------
extern "C" void kernel_launch(void* const* d_in, const int* in_sizes, int n_in,
                              void* d_out, int out_size, void* d_ws, size_t ws_size,
                              hipStream_t stream) {
    const int*   x_idx = (const int*)  d_in[0];
    const float* emb   = (const float*)d_in[1];
    const float* Wih1  = (const float*)d_in[2];
    const float* Whh1  = (const float*)d_in[3];
    const float* bih1  = (const float*)d_in[4];
    const float* bhh1  = (const float*)d_in[5];
    const float* Wih2  = (const float*)d_in[6];
    const float* Whh2  = (const float*)d_in[7];
    const float* bih2  = (const float*)d_in[8];
    const float* bhh2  = (const float*)d_in[9];
    const float* fcw   = (const float*)d_in[10];
    const float* fcb   = (const float*)d_in[11];
    float* out = (float*)d_out;

    float* table = (float*)d_ws;                       // 21*260*4 = 21840 B
    float* x2    = (float*)((char*)d_ws + 32768);      // 1024*100*64*4 = 26.2 MB

    k_table<<<VOCAB, 256, 0, stream>>>(Wih1, emb, bih1, bhh1, table);
    k_lstm1<<<NB / 16, 512, 0, stream>>>(x_idx, Whh1, table, x2);
    k_lstm2<<<NB / 16, 512, 0, stream>>>(x2, Wih2, Whh2, bih2, bhh2, fcw, fcb, out);
}